// Round 4
// baseline (413.977 us; speedup 1.0000x reference)
//
#include <hip/hip_runtime.h>
#include <hip/hip_bf16.h>
#include <cstdint>

// Problem constants
#define B_ 4
#define T_ 1024
#define W_ 33
#define F_ 512
#define H_ 8
#define DK_ 64

typedef __attribute__((ext_vector_type(8))) short short8;
typedef __attribute__((ext_vector_type(4))) float f32x4;

__device__ __forceinline__ float b2f(ushort u) {
  return __uint_as_float(((uint32_t)u) << 16);
}
__device__ __forceinline__ ushort f2b(float f) {
  union { __hip_bfloat16 b; ushort u; } cv;
  cv.b = __float2bfloat16(f);
  return cv.u;
}

// ---------------------------------------------------------------------------
// Weight convert: W[k][n] f32 -> bf16 in MFMA *fragment order*:
//   dst[((nt*16 + kc)*64 + lane)*8 + e] = W[k][n]
//   with n = nt*16 + (lane&15), k = kc*32 + (lane>>4)*8 + e.
// ---------------------------------------------------------------------------
__global__ void convert_w(const float* __restrict__ Wq, const float* __restrict__ Wk,
                          const float* __restrict__ Wv, const float* __restrict__ Wo,
                          ushort* __restrict__ out)
{
  int which = blockIdx.y;
  const float* src = (which == 0) ? Wq : (which == 1) ? Wk : (which == 2) ? Wv : Wo;
  ushort* dst = out + (size_t)which * 262144;
  int idx = blockIdx.x * 256 + threadIdx.x;     // 0 .. 262143
  int e  = idx & 7;
  int l  = (idx >> 3) & 63;
  int kc = (idx >> 9) & 15;
  int nt = idx >> 13;
  int k = kc * 32 + ((l >> 4) << 3) + e;
  int n = (nt << 4) + (l & 15);
  dst[idx] = f2b(src[k * 512 + n]);
}

// ---------------------------------------------------------------------------
// GEMM: C[M x 512] = A[M x 512] * W[512 x 512] + bias.
// BM=128, BN=128, BK=64, 4 waves (2x2), wave tile 64x64.
// Deep pipeline, per K-step t:
//   lwrite buf[(t+1)%3] <- P[(t+1)&1] (A issued 2 steps ago; vmcnt ~free)
//   issue A(t+2) -> P[t&1]            (HBM; 2 phases to cover)
//   load  B(t+1) -> Q[(t+1)&1]        (L2; 1 phase to cover)
//   compute t from buf[t%3] + Q[t&1]  (waits nothing recent)
//   barrier
// 3 LDS buffers (48 KB) make the early write race-free with one barrier/step.
// B: no LDS, fragment-ordered global (L2-resident), coalesced dwordx4.
// Bijective XCD swizzle (m204): 4 bn-siblings of each M-tile consecutive on
// one XCD -> A fetched from HBM once, reused via that XCD's L2.
// ---------------------------------------------------------------------------
template<bool A_F32, bool OUT_F32>
__global__ __launch_bounds__(256, 2)
void gemm_kernel(const void* __restrict__ A0p, const void* __restrict__ A1p,
                 const ushort* __restrict__ B0, const ushort* __restrict__ B1,
                 const float* __restrict__ bias0, const float* __restrict__ bias1,
                 void* __restrict__ C0, void* __restrict__ C1)
{
  __shared__ ushort lA[3][128 * 64];   // 3 x 16 KB

  const int tid  = threadIdx.x;
  const int lane = tid & 63;
  const int wid  = tid >> 6;
  const int wr   = wid >> 1, wc = wid & 1;
  const int lrow = lane & 15;
  const int lk8  = (lane >> 4) * 8;

  const void* Ap; const ushort* Bf; const float* bias; void* Cp;
  if (blockIdx.y == 0) { Ap = A0p; Bf = B0; bias = bias0; Cp = C0; }
  else                 { Ap = A1p; Bf = B1; bias = bias1; Cp = C1; }

  // bijective XCD swizzle: consecutive L on one XCD; bn = L&3 fastest
  {
  }
  int nwg  = gridDim.x;
  int xcd  = blockIdx.x & 7;
  int slot = blockIdx.x >> 3;
  int q8   = nwg >> 3, r8 = nwg & 7;
  int base = (xcd < r8) ? xcd * (q8 + 1) : r8 * (q8 + 1) + (xcd - r8) * q8;
  int L    = base + slot;
  int bm   = L >> 2;
  int bn   = L & 3;

  // per-thread A staging geometry: 4 chunks of 8 bf16 (tile 128 x 64)
  int lb_[4];
  size_t asrc_[4];
#pragma unroll
  for (int p = 0; p < 4; ++p) {
    int c   = p * 256 + tid;
    int row = c >> 3;               // 0..127
    int kc  = (c & 7) * 8;          // 0..56
    lb_[p]  = (row * 128 + kc * 2) ^ ((row & 7) << 4);
    asrc_[p] = (size_t)(bm * 128 + row) * 512 + kc;
  }

  const int ntb = bn * 8 + wc * 4;   // wave's base n-tile (of 32)

  // A reg stage buffers (2-deep) and B fragment buffers (2-deep)
  float4 P0a0[4], P0a1[4], P1a0[4], P1a1[4];
  short8 P0r[4], P1r[4];
  short8 Q0[8], Q1[8];

  auto issueA = [&](int ks, float4 (&d0)[4], float4 (&d1)[4], short8 (&dr)[4]) {
#pragma unroll
    for (int p = 0; p < 4; ++p) {
      if (A_F32) {
        const float* src = (const float*)Ap + asrc_[p] + ks * 64;
        d0[p] = *(const float4*)src;
        d1[p] = *(const float4*)(src + 4);
      } else {
        dr[p] = *(const short8*)((const ushort*)Ap + asrc_[p] + ks * 64);
      }
    }
  };
  auto lwriteA = [&](int buf, float4 (&d0)[4], float4 (&d1)[4], short8 (&dr)[4]) {
#pragma unroll
    for (int p = 0; p < 4; ++p) {
      short8 hv;
      if (A_F32) {
        hv[0] = (short)f2b(d0[p].x); hv[1] = (short)f2b(d0[p].y);
        hv[2] = (short)f2b(d0[p].z); hv[3] = (short)f2b(d0[p].w);
        hv[4] = (short)f2b(d1[p].x); hv[5] = (short)f2b(d1[p].y);
        hv[6] = (short)f2b(d1[p].z); hv[7] = (short)f2b(d1[p].w);
      } else {
        hv = dr[p];
      }
      *(short8*)((char*)lA[buf] + lb_[p]) = hv;
    }
  };
  auto loadB = [&](int ks, short8 (&dq)[8]) {
#pragma unroll
    for (int kk = 0; kk < 2; ++kk)
#pragma unroll
      for (int nf = 0; nf < 4; ++nf)
        dq[kk * 4 + nf] = *(const short8*)(Bf +
            (((size_t)(ntb + nf) * 16 + ks * 2 + kk) * 64 + lane) * 8);
  };

  f32x4 acc[4][4];
#pragma unroll
  for (int i = 0; i < 4; ++i)
#pragma unroll
    for (int j = 0; j < 4; ++j) acc[i][j] = {0.f, 0.f, 0.f, 0.f};

  auto computeStep = [&](int buf, short8 (&dq)[8]) {
#pragma unroll
    for (int kk = 0; kk < 2; ++kk) {
      short8 af[4];
#pragma unroll
      for (int mf = 0; mf < 4; ++mf) {
        int row = wr * 64 + mf * 16 + lrow;
        int off = (row * 128 + (kk * 32 + lk8) * 2) ^ ((row & 7) << 4);
        af[mf] = *(const short8*)((const char*)lA[buf] + off);
      }
#pragma unroll
      for (int mf = 0; mf < 4; ++mf)
#pragma unroll
        for (int nf = 0; nf < 4; ++nf)
          acc[mf][nf] = __builtin_amdgcn_mfma_f32_16x16x32_bf16(af[mf], dq[kk * 4 + nf], acc[mf][nf], 0, 0, 0);
    }
  };

  // prologue: A(0)->P0, A(1)->P1, B(0)->Q0, publish buf0
  issueA(0, P0a0, P0a1, P0r);
  issueA(1, P1a0, P1a1, P1r);
  loadB(0, Q0);
  lwriteA(0, P0a0, P0a1, P0r);     // waits A(0) only (A(1),B(0) stay in flight)
  __syncthreads();

#define GSTEP(T, PWa0, PWa1, PWr, PIa0, PIa1, PIr, QW, QR)                    \
  {                                                                           \
    if ((T) + 1 < 8) lwriteA(((T) + 1) % 3, PWa0, PWa1, PWr);                 \
    if ((T) + 2 < 8) issueA((T) + 2, PIa0, PIa1, PIr);                        \
    if ((T) + 1 < 8) loadB((T) + 1, QW);                                      \
    computeStep((T) % 3, QR);                                                 \
    if ((T) < 7) __syncthreads();                                             \
  }

  GSTEP(0, P1a0, P1a1, P1r, P0a0, P0a1, P0r, Q1, Q0)
  GSTEP(1, P0a0, P0a1, P0r, P1a0, P1a1, P1r, Q0, Q1)
  GSTEP(2, P1a0, P1a1, P1r, P0a0, P0a1, P0r, Q1, Q0)
  GSTEP(3, P0a0, P0a1, P0r, P1a0, P1a1, P1r, Q0, Q1)
  GSTEP(4, P1a0, P1a1, P1r, P0a0, P0a1, P0r, Q1, Q0)
  GSTEP(5, P0a0, P0a1, P0r, P1a0, P1a1, P1r, Q0, Q1)
  GSTEP(6, P1a0, P1a1, P1r, P0a0, P0a1, P0r, Q1, Q0)
  GSTEP(7, P0a0, P0a1, P0r, P1a0, P1a1, P1r, Q0, Q1)
#undef GSTEP

  // ---- epilogue: bias + store ----
  float bs[4];
#pragma unroll
  for (int nf = 0; nf < 4; ++nf)
    bs[nf] = bias[bn * 128 + wc * 64 + nf * 16 + lrow];

  const int r0 = (lane >> 4) * 4;
#pragma unroll
  for (int mf = 0; mf < 4; ++mf) {
#pragma unroll
    for (int nf = 0; nf < 4; ++nf) {
      int gcol = bn * 128 + wc * 64 + nf * 16 + lrow;
#pragma unroll
      for (int r = 0; r < 4; ++r) {
        int grow = bm * 128 + wr * 64 + mf * 16 + r0 + r;
        float val = acc[mf][nf][r] + bs[nf];
        if (OUT_F32) ((float*)Cp)[(size_t)grow * 512 + gcol] = val;
        else         ((ushort*)Cp)[(size_t)grow * 512 + gcol] = f2b(val);
      }
    }
  }
}

// ---------------------------------------------------------------------------
// Attention: one block per (b,t). k/v rows for this t staged in LDS.
// ---------------------------------------------------------------------------
__global__ __launch_bounds__(256, 2)
void attn_kernel(const ushort* __restrict__ q, const ushort* __restrict__ k,
                 const ushort* __restrict__ v, const int* __restrict__ mask,
                 ushort* __restrict__ x, int bt0)
{
  __shared__ ushort lk[W_][520];
  __shared__ ushort lv[W_][520];
  __shared__ ushort lq[512];
  __shared__ float  sc[H_][W_];
  __shared__ float  aw[H_][W_];
  __shared__ float  mx[H_], inv[H_];
  __shared__ int    msk[W_];

  const int tid = threadIdx.x;
  const int bt  = blockIdx.x + bt0;        // global b*T + t

  if (tid < 64) ((short8*)lq)[tid] = ((const short8*)(q + (size_t)bt * 512))[tid];
  if (tid < W_) msk[tid] = mask[(size_t)bt * W_ + tid];

  size_t kvbase = (size_t)blockIdx.x * (W_ * 512);
  for (int c = tid; c < W_ * 64; c += 256) {
    int w  = c >> 6;
    int d8 = (c & 63) * 8;
    *(short8*)&lk[w][d8] = *(const short8*)(k + kvbase + w * 512 + d8);
    *(short8*)&lv[w][d8] = *(const short8*)(v + kvbase + w * 512 + d8);
  }
  __syncthreads();

  for (int task = tid; task < H_ * W_; task += 256) {
    int h = task / W_, w = task % W_;
    const ushort* kr = &lk[w][h * 64];
    const ushort* qr = &lq[h * 64];
    float s = 0.f;
#pragma unroll
    for (int d8 = 0; d8 < 8; ++d8) {
      short8 qv = *(const short8*)(qr + d8 * 8);
      short8 kv = *(const short8*)(kr + d8 * 8);
#pragma unroll
      for (int j = 0; j < 8; ++j) s += b2f((ushort)qv[j]) * b2f((ushort)kv[j]);
    }
    s *= 0.125f;
    sc[h][w] = msk[w] ? s : -3.4028234663852886e38f;
  }
  __syncthreads();

  if (tid < H_) {
    float m = -3.4028234663852886e38f;
    for (int w = 0; w < W_; ++w) m = fmaxf(m, sc[tid][w]);
    float ssum = 0.f;
    for (int w = 0; w < W_; ++w) ssum += __expf(sc[tid][w] - m);
    mx[tid] = m;
    inv[tid] = 1.f / ssum;
  }
  __syncthreads();

  for (int task = tid; task < H_ * W_; task += 256) {
    int h = task / W_, w = task % W_;
    aw[h][w] = msk[w] ? __expf(sc[h][w] - mx[h]) * inv[h] : 0.f;
  }
  __syncthreads();

  for (int f = tid; f < 512; f += 256) {
    int h = f >> 6, d = f & 63;
    float a = 0.f;
#pragma unroll
    for (int w = 0; w < W_; ++w) a += aw[h][w] * b2f(lv[w][h * 64 + d]);
    x[(size_t)bt * 512 + f] = f2b(a);
  }
}

// ---------------------------------------------------------------------------
extern "C" void kernel_launch(void* const* d_in, const int* in_sizes, int n_in,
                              void* d_out, int out_size, void* d_ws, size_t ws_size,
                              hipStream_t stream)
{
  const float* query = (const float*)d_in[0];
  const float* key   = (const float*)d_in[1];
  const float* value = (const float*)d_in[2];
  const int*   mask  = (const int*)d_in[3];
  const float* Wq    = (const float*)d_in[4];
  const float* bq    = (const float*)d_in[5];
  const float* Wk    = (const float*)d_in[6];
  const float* bk    = (const float*)d_in[7];
  const float* Wv    = (const float*)d_in[8];
  const float* bv    = (const float*)d_in[9];
  const float* Wo    = (const float*)d_in[10];
  const float* bo    = (const float*)d_in[11];

  char* ws = (char*)d_ws;
  ushort* Wt   = (ushort*)ws;                         // 4 x 512x512 bf16 = 2 MB
  ushort* Wtq  = Wt;
  ushort* Wtk  = Wt + 262144;
  ushort* Wtv  = Wt + 524288;
  ushort* Wto  = Wt + 786432;
  ushort* qws  = (ushort*)(ws + 2 * 1024 * 1024);     // 4 MB
  ushort* xws  = (ushort*)(ws + 6 * 1024 * 1024);     // 4 MB
  ushort* kvws = (ushort*)(ws + 10 * 1024 * 1024);

  // chunk the (b*T) dimension so k/v bf16 intermediates fit in ws
  size_t fixed = 10ull * 1024 * 1024;
  size_t avail = ws_size > fixed ? ws_size - fixed : 0;
  long trl = (long)(avail / (2ull * W_ * 512 * 2));   // t-rows that fit
  int TR = (int)(trl / 128) * 128;
  if (TR > B_ * T_) TR = B_ * T_;
  if (TR < 128) TR = 128;
  ushort* kws = kvws;
  ushort* vws = kvws + (size_t)TR * W_ * 512;

  convert_w<<<dim3(1024, 4), 256, 0, stream>>>(Wq, Wk, Wv, Wo, Wt);

  // Q projection: M=4096 -> 32 M-tiles
  gemm_kernel<true, false><<<dim3(128, 1), 256, 0, stream>>>(
      query, query, Wtq, Wtq, bq, bq, qws, qws);

  for (int bt0 = 0; bt0 < B_ * T_; bt0 += TR) {
    int rows = B_ * T_ - bt0; if (rows > TR) rows = TR;
    int Mt = rows * W_ / 128;              // rows is a multiple of 128
    const float* kptr = key   + (size_t)bt0 * W_ * 512;
    const float* vptr = value + (size_t)bt0 * W_ * 512;
    // K-proj and V-proj merged into one dispatch (blockIdx.y selects)
    gemm_kernel<true, false><<<dim3(Mt * 4, 2), 256, 0, stream>>>(
        kptr, vptr, Wtk, Wtv, bk, bv, kws, vws);
    attn_kernel<<<rows, 256, 0, stream>>>(qws, kws, vws, mask, xws, bt0);
  }

  // output projection: x @ Wo + bo -> f32 d_out
  gemm_kernel<false, true><<<dim3(128, 1), 256, 0, stream>>>(
      xws, xws, Wto, Wto, bo, bo, d_out, d_out);
}